// Round 6
// baseline (387.074 us; speedup 1.0000x reference)
//
#include <hip/hip_runtime.h>

#define HIDDEN 2048
#define NH 16
#define NKV 4
#define HD 128
#define BATCH 2
#define SEQ 2048
#define MROWS (BATCH*SEQ)          // 4096
#define NQKV (NH*HD + 2*NKV*HD)    // 3072
#define KOFF (NH*HD)               // 2048
#define VOFF (NH*HD + NKV*HD)      // 2560

typedef unsigned short u16;
typedef unsigned int u32;
typedef __bf16 bf16_t;
typedef bf16_t bf16x8 __attribute__((ext_vector_type(8)));
typedef float f32x4 __attribute__((ext_vector_type(4)));
typedef u16 u16x8 __attribute__((ext_vector_type(8)));

__device__ __forceinline__ u16 f2bf(float f) {
  return __builtin_bit_cast(u16, (__bf16)f);   // compiler RNE (m240: don't hand-write)
}
__device__ __forceinline__ float bf2f(u16 h) {
  u32 u = ((u32)h) << 16;
  return __builtin_bit_cast(float, u);
}

// ---------------- cast f32 -> bf16, 8 elems/thread ----------------
__global__ void cast_f32_bf16(const float* __restrict__ in, u16* __restrict__ out, int n8) {
  int i = blockIdx.x * blockDim.x + threadIdx.x;
  if (i >= n8) return;
  const float4* p = (const float4*)in + (size_t)i * 2;
  float4 a = p[0], b = p[1];
  u16x8 o;
  o[0]=f2bf(a.x); o[1]=f2bf(a.y); o[2]=f2bf(a.z); o[3]=f2bf(a.w);
  o[4]=f2bf(b.x); o[5]=f2bf(b.y); o[6]=f2bf(b.z); o[7]=f2bf(b.w);
  *((u16x8*)out + i) = o;
}

// ---------------- transpose + cast: src K x N f32 -> dst N x K bf16 ----------------
__global__ void transpose_cast(const float* __restrict__ src, u16* __restrict__ dst, int K, int N) {
  __shared__ float tile[32][33];
  int k0 = blockIdx.y * 32, n0 = blockIdx.x * 32;
  int tx = threadIdx.x, ty = threadIdx.y;
  #pragma unroll
  for (int j = 0; j < 32; j += 8)
    tile[ty + j][tx] = src[(size_t)(k0 + ty + j) * N + n0 + tx];
  __syncthreads();
  #pragma unroll
  for (int j = 0; j < 32; j += 8)
    dst[(size_t)(n0 + ty + j) * K + k0 + tx] = f2bf(tile[tx][ty + j]);
}

// ---------------- GEMM 256x256 tile, BK=64, 8 waves (2x4), swizzled LDS ----------------
// C[M,N] = A[M,K] * Bt[N,K]^T, bf16 in, f32 acc.
// LDS layout per tile: [256 rows][8 chunks of 16B]; chunk slot = cc ^ (row&7).
// Stage: global_load_lds linear dest + inverse-swizzled global source (rule 21).
// One __syncthreads per iteration; stage of T_{i+1} issued at iteration top
// (distance ~full iteration >> L2 latency, so the pre-barrier vmcnt drain is free).
template<int OUT_BF16>
__global__ __launch_bounds__(512, 2) void gemm256(const u16* __restrict__ A, const u16* __restrict__ Bt,
                                                  void* __restrict__ Cout, int M, int N, int K) {
  __shared__ u16 As[2][256 * 64];
  __shared__ u16 Bs[2][256 * 64];
  const int tid = threadIdx.x;
  const int lane = tid & 63, wave = tid >> 6;
  const int mb = blockIdx.y * 256, nb = blockIdx.x * 256;
  const int wm = (wave >> 2) * 128;      // 2 M-waves
  const int wn = (wave & 3) * 64;        // 4 N-waves
  const int NT = K >> 6;

  // stage source precompute: chunk c = j*512 + tid -> row = j*64 + (tid>>3), slot = tid&7
  const int rsub = tid >> 3;
  const int scol = (tid & 7) ^ (rsub & 7);     // inverse swizzle (involution)
  const int wbase = (tid & ~63);               // wave*64, wave-uniform

  auto stage = [&](int buf, int kt) {
    #pragma unroll
    for (int j = 0; j < 4; ++j) {
      int r = j * 64 + rsub;
      const u16* ga = A + (size_t)(mb + r) * K + kt * 64 + scol * 8;
      __builtin_amdgcn_global_load_lds((const __attribute__((address_space(1))) u32*)ga,
          (__attribute__((address_space(3))) u32*)&As[buf][(j * 512 + wbase) * 8], 16, 0, 0);
      const u16* gb = Bt + (size_t)(nb + r) * K + kt * 64 + scol * 8;
      __builtin_amdgcn_global_load_lds((const __attribute__((address_space(1))) u32*)gb,
          (__attribute__((address_space(3))) u32*)&Bs[buf][(j * 512 + wbase) * 8], 16, 0, 0);
    }
  };

  f32x4 acc[8][4];
  #pragma unroll
  for (int i = 0; i < 8; ++i)
    #pragma unroll
    for (int j = 0; j < 4; ++j) acc[i][j] = (f32x4)0.0f;

  // frag read: row-local = base+ (lane&15); chunk = (ks*4 + (lane>>4)) ^ (lane&7)
  const int arow = (lane & 15) * 64;
  const int axor = lane & 7;
  const int asel = lane >> 4;

  stage(0, 0);
  __syncthreads();
  for (int i = 0; i < NT; ++i) {
    int cur = i & 1;
    if (i + 1 < NT) stage(cur ^ 1, i + 1);

    bf16x8 af[4][2], bfr[2][2];
    // ---- m-lo frags (mi 0..3) + n-lo frags (ni 0..1) ----
    #pragma unroll
    for (int mi = 0; mi < 4; ++mi)
      #pragma unroll
      for (int ks = 0; ks < 2; ++ks)
        af[mi][ks] = __builtin_bit_cast(bf16x8,
          *(const u16x8*)&As[cur][(wm + mi * 16) * 64 + arow + (((ks * 4 + asel)) ^ axor) * 8]);
    #pragma unroll
    for (int ni = 0; ni < 2; ++ni)
      #pragma unroll
      for (int ks = 0; ks < 2; ++ks)
        bfr[ni][ks] = __builtin_bit_cast(bf16x8,
          *(const u16x8*)&Bs[cur][(wn + ni * 16) * 64 + arow + (((ks * 4 + asel)) ^ axor) * 8]);
    __builtin_amdgcn_s_setprio(1);
    #pragma unroll
    for (int mi = 0; mi < 4; ++mi)
      #pragma unroll
      for (int ni = 0; ni < 2; ++ni)
        #pragma unroll
        for (int ks = 0; ks < 2; ++ks)
          acc[mi][ni] = __builtin_amdgcn_mfma_f32_16x16x32_bf16(af[mi][ks], bfr[ni][ks], acc[mi][ni], 0, 0, 0);
    __builtin_amdgcn_s_setprio(0);
    // ---- n-hi frags (ni 2..3), reuse af ----
    #pragma unroll
    for (int ni = 0; ni < 2; ++ni)
      #pragma unroll
      for (int ks = 0; ks < 2; ++ks)
        bfr[ni][ks] = __builtin_bit_cast(bf16x8,
          *(const u16x8*)&Bs[cur][(wn + (2 + ni) * 16) * 64 + arow + (((ks * 4 + asel)) ^ axor) * 8]);
    __builtin_amdgcn_s_setprio(1);
    #pragma unroll
    for (int mi = 0; mi < 4; ++mi)
      #pragma unroll
      for (int ni = 0; ni < 2; ++ni)
        #pragma unroll
        for (int ks = 0; ks < 2; ++ks)
          acc[mi][2 + ni] = __builtin_amdgcn_mfma_f32_16x16x32_bf16(af[mi][ks], bfr[ni][ks], acc[mi][2 + ni], 0, 0, 0);
    __builtin_amdgcn_s_setprio(0);
    // ---- m-hi frags (mi 4..7), reuse bfr(n-hi) ----
    #pragma unroll
    for (int mi = 0; mi < 4; ++mi)
      #pragma unroll
      for (int ks = 0; ks < 2; ++ks)
        af[mi][ks] = __builtin_bit_cast(bf16x8,
          *(const u16x8*)&As[cur][(wm + (4 + mi) * 16) * 64 + arow + (((ks * 4 + asel)) ^ axor) * 8]);
    __builtin_amdgcn_s_setprio(1);
    #pragma unroll
    for (int mi = 0; mi < 4; ++mi)
      #pragma unroll
      for (int ni = 0; ni < 2; ++ni)
        #pragma unroll
        for (int ks = 0; ks < 2; ++ks)
          acc[4 + mi][2 + ni] = __builtin_amdgcn_mfma_f32_16x16x32_bf16(af[mi][ks], bfr[ni][ks], acc[4 + mi][2 + ni], 0, 0, 0);
    __builtin_amdgcn_s_setprio(0);
    // ---- n-lo frags again, reuse af(m-hi) ----
    #pragma unroll
    for (int ni = 0; ni < 2; ++ni)
      #pragma unroll
      for (int ks = 0; ks < 2; ++ks)
        bfr[ni][ks] = __builtin_bit_cast(bf16x8,
          *(const u16x8*)&Bs[cur][(wn + ni * 16) * 64 + arow + (((ks * 4 + asel)) ^ axor) * 8]);
    __builtin_amdgcn_s_setprio(1);
    #pragma unroll
    for (int mi = 0; mi < 4; ++mi)
      #pragma unroll
      for (int ni = 0; ni < 2; ++ni)
        #pragma unroll
        for (int ks = 0; ks < 2; ++ks)
          acc[4 + mi][ni] = __builtin_amdgcn_mfma_f32_16x16x32_bf16(af[mi][ks], bfr[ni][ks], acc[4 + mi][ni], 0, 0, 0);
    __builtin_amdgcn_s_setprio(0);

    __syncthreads();
  }
  // epilogue: C/D layout col = lane&15, row = (lane>>4)*4 + reg
  int rbase = mb + wm + (lane >> 4) * 4;
  int cbase = nb + wn + (lane & 15);
  #pragma unroll
  for (int mi = 0; mi < 8; ++mi) {
    #pragma unroll
    for (int r = 0; r < 4; ++r) {
      int row = rbase + mi * 16 + r;
      #pragma unroll
      for (int ni = 0; ni < 4; ++ni) {
        int col = cbase + ni * 16;
        float v = acc[mi][ni][r];
        if (OUT_BF16) ((u16*)Cout)[(size_t)row * N + col] = f2bf(v);
        else          ((float*)Cout)[(size_t)row * N + col] = v;
      }
    }
  }
}

// ---------------- RoPE in-place on QKV (bf16), Q heads 0..15, K heads 0..3 ----------------
__global__ void rope_kernel(u16* __restrict__ qkv) {
  int idx = blockIdx.x * blockDim.x + threadIdx.x;   // < MROWS*20*64
  int d = idx & 63;
  int t = idx >> 6;
  int hd = t % 20;
  int row = t / 20;
  int s = row & (SEQ - 1);
  int cb = (hd < NH) ? hd * HD : KOFF + (hd - NH) * HD;
  float inv = __expf((float)d * -0.14391156f);   // 10000^(-d/64)
  float freq = (float)s * inv;
  float sn = sinf(freq), cs = cosf(freq);
  size_t base = (size_t)row * NQKV + cb + d;
  float x0 = bf2f(qkv[base]), x1 = bf2f(qkv[base + 64]);
  qkv[base]      = f2bf(x0 * cs - x1 * sn);
  qkv[base + 64] = f2bf(x1 * cs + x0 * sn);
}

// ---------------- transpose V section of QKV into VT (b,kvh,d,s) ----------------
__global__ void vtrans_kernel(const u16* __restrict__ qkv, u16* __restrict__ vt) {
  __shared__ u16 tile[32][33];
  int bh = blockIdx.z;            // b*NKV + kvh
  int d0 = blockIdx.y * 32;
  int s0 = blockIdx.x * 32;
  int b = bh >> 2, kvh = bh & 3;
  int tx = threadIdx.x, ty = threadIdx.y;
  const u16* src = qkv + (size_t)(b * SEQ) * NQKV + VOFF + kvh * HD;
  #pragma unroll
  for (int j = 0; j < 32; j += 8)
    tile[ty + j][tx] = src[(size_t)(s0 + ty + j) * NQKV + d0 + tx];
  __syncthreads();
  u16* dst = vt + (size_t)bh * HD * SEQ;
  #pragma unroll
  for (int j = 0; j < 32; j += 8)
    dst[(size_t)(d0 + ty + j) * SEQ + s0 + tx] = tile[tx][ty + j];
}

// ---------------- flash attention, causal, GQA, paired q-tiles ----------------
// grid (16, NH, B) = 512 blocks, 256 threads = 4 waves -> 2 blocks/CU (LDS 72KB).
// Block owns q-tiles qtA = blockIdx.x, qtB = 31 - qtA (QBLK=64): 33 ctx-units each.
__global__ __launch_bounds__(256, 2) void attn_kernel(const u16* __restrict__ qkv,
                                                      const u16* __restrict__ vt,
                                                      u16* __restrict__ out) {
  __shared__ u16 Ks[2][64 * 128];   // [kv][d], 256B rows, slot ^= kv&7
  __shared__ u16 Vs[2][128 * 64];   // [d][kv], 128B rows, slot ^= d&7
  __shared__ u16 Ps[4][16 * 64];    // per-wave [q][kv], 128B rows, slot ^= q&7
  const int tid = threadIdx.x, lane = tid & 63, wave = tid >> 6;
  const int qtA = blockIdx.x, qtB = 31 - qtA;
  const int h = blockIdx.y, b = blockIdx.z;
  const int kvh = h >> 2;
  const int q0A = qtA * 64 + wave * 16;
  const int q0B = qtB * 64 + wave * 16;
  const float scale2 = 0.12751743f;  // 1/sqrt(128) * log2(e)  (exp2-domain softmax)

  const u16* kbase = qkv + (size_t)(b * SEQ) * NQKV + KOFF + kvh * HD;
  const u16* vbase = vt + (size_t)(b * NKV + kvh) * HD * SEQ;

  // Q fragments (A layout: row = lane&15, k = 8*(lane>>4)+e)
  bf16x8 qfA[4], qfB[4];
  {
    const u16* qa = qkv + (size_t)(b * SEQ + q0A + (lane & 15)) * NQKV + h * HD + (lane >> 4) * 8;
    const u16* qb = qkv + (size_t)(b * SEQ + q0B + (lane & 15)) * NQKV + h * HD + (lane >> 4) * 8;
    #pragma unroll
    for (int kc = 0; kc < 4; ++kc) {
      qfA[kc] = __builtin_bit_cast(bf16x8, *(const u16x8*)(qa + kc * 32));
      qfB[kc] = __builtin_bit_cast(bf16x8, *(const u16x8*)(qb + kc * 32));
    }
  }
  f32x4 oaccA[8], oaccB[8];
  float mA[4], lA[4], mB[4], lB[4];
  #pragma unroll
  for (int i = 0; i < 8; ++i) { oaccA[i] = (f32x4)0.0f; oaccB[i] = (f32x4)0.0f; }
  #pragma unroll
  for (int r = 0; r < 4; ++r) { mA[r] = -INFINITY; lA[r] = 0.0f; mB[r] = -INFINITY; lB[r] = 0.0f; }

  // staging precompute (256 threads):
  // K tile 64x128 u16 = 1024 chunks (16/row): c = j*256+tid -> row j*16+(tid>>4), slot tid&15
  const int krow = tid >> 4;
  const int kslot = (tid & 15) ^ (krow & 7);
  // V tile 128x64 u16 = 1024 chunks (8/row): c = j*256+tid -> row j*32+(tid>>3), slot tid&7
  const int vrow = tid >> 3;
  const int vslot = (tid & 7) ^ (vrow & 7);
  const int wbase = (tid & ~63);   // wave-uniform chunk base

  auto stage = [&](int buf, int t) {
    int kv0 = t * 64;
    #pragma unroll
    for (int j = 0; j < 4; ++j) {
      const u16* src = kbase + (size_t)(kv0 + j * 16 + krow) * NQKV + kslot * 8;
      __builtin_amdgcn_global_load_lds((const __attribute__((address_space(1))) u32*)src,
          (__attribute__((address_space(3))) u32*)&Ks[buf][(j * 256 + wbase) * 8], 16, 0, 0);
    }
    #pragma unroll
    for (int j = 0; j < 4; ++j) {
      const u16* src = vbase + (size_t)(j * 32 + vrow) * SEQ + kv0 + vslot * 8;
      __builtin_amdgcn_global_load_lds((const __attribute__((address_space(1))) u32*)src,
          (__attribute__((address_space(3))) u32*)&Vs[buf][(j * 256 + wbase) * 8], 16, 0, 0);
    }
  };

  // one context's QK^T + online softmax (exp2 domain, defer-max) + PV
  auto do_ctx = [&](const bf16x8 (&qf)[4], f32x4 (&oacc)[8], float (&mr)[4], float (&lr)[4],
                    int q0c, int kv0, int cur) {
    f32x4 sacc[4];
    #pragma unroll
    for (int n2 = 0; n2 < 4; ++n2) sacc[n2] = (f32x4)0.0f;
    #pragma unroll
    for (int n2 = 0; n2 < 4; ++n2) {
      int kvr = n2 * 16 + (lane & 15);
      #pragma unroll
      for (int kc = 0; kc < 4; ++kc) {
        int ch = (kc * 4 + (lane >> 4)) ^ (kvr & 7);
        bf16x8 kf = __builtin_bit_cast(bf16x8, *(const u16x8*)&Ks[cur][kvr * 128 + ch * 8]);
        sacc[n2] = __builtin_amdgcn_mfma_f32_16x16x32_bf16(qf[kc], kf, sacc[n2], 0, 0, 0);
      }
    }
    const bool full = (kv0 + 63 <= q0c);   // wave-uniform: no causal mask needed
    u16* pwb = &Ps[wave][0];
    #pragma unroll
    for (int r = 0; r < 4; ++r) {
      int qr = (lane >> 4) * 4 + r;
      float p0, p1, p2, p3;
      if (full) {
        p0 = sacc[0][r] * scale2; p1 = sacc[1][r] * scale2;
        p2 = sacc[2][r] * scale2; p3 = sacc[3][r] * scale2;
      } else {
        int q = q0c + qr;
        int kvc = kv0 + (lane & 15);
        p0 = (kvc       <= q) ? sacc[0][r] * scale2 : -INFINITY;
        p1 = (kvc + 16  <= q) ? sacc[1][r] * scale2 : -INFINITY;
        p2 = (kvc + 32  <= q) ? sacc[2][r] * scale2 : -INFINITY;
        p3 = (kvc + 48  <= q) ? sacc[3][r] * scale2 : -INFINITY;
      }
      float v = fmaxf(fmaxf(p0, p1), fmaxf(p2, p3));
      v = fmaxf(v, __shfl_xor(v, 1));
      v = fmaxf(v, __shfl_xor(v, 2));
      v = fmaxf(v, __shfl_xor(v, 4));
      v = fmaxf(v, __shfl_xor(v, 8));
      float m = mr[r];
      if (v > m + 8.0f) {            // defer-max: P bounded by 2^8
        float corr = exp2f(m - v);
        lr[r] *= corr;
        #pragma unroll
        for (int nt = 0; nt < 8; ++nt) oacc[nt][r] *= corr;
        m = v; mr[r] = v;
      }
      float e0 = exp2f(p0 - m), e1 = exp2f(p1 - m);
      float e2 = exp2f(p2 - m), e3 = exp2f(p3 - m);
      float ps = (e0 + e1) + (e2 + e3);
      ps += __shfl_xor(ps, 1);
      ps += __shfl_xor(ps, 2);
      ps += __shfl_xor(ps, 4);
      ps += __shfl_xor(ps, 8);
      lr[r] += ps;
      // P -> LDS at swizzled addr: row qr (128B), col n2*16+(lane&15)
      char* base = (char*)pwb + qr * 128 + (lane & 7) * 2;
      int half = (lane & 15) >> 3;
      *(u16*)(base + (((0 + half) ^ (qr & 7)) << 4)) = f2bf(e0);
      *(u16*)(base + (((2 + half) ^ (qr & 7)) << 4)) = f2bf(e1);
      *(u16*)(base + (((4 + half) ^ (qr & 7)) << 4)) = f2bf(e2);
      *(u16*)(base + (((6 + half) ^ (qr & 7)) << 4)) = f2bf(e3);
    }
    asm volatile("s_waitcnt lgkmcnt(0)" ::: "memory");
    bf16x8 pf[2];
    #pragma unroll
    for (int k2 = 0; k2 < 2; ++k2) {
      int q = lane & 15;
      int ch = (k2 * 4 + (lane >> 4)) ^ (q & 7);
      pf[k2] = __builtin_bit_cast(bf16x8, *(const u16x8*)((const char*)pwb + q * 128 + ch * 16));
    }
    #pragma unroll
    for (int nt = 0; nt < 8; ++nt) {
      int d = nt * 16 + (lane & 15);
      #pragma unroll
      for (int k2 = 0; k2 < 2; ++k2) {
        int ch = (k2 * 4 + (lane >> 4)) ^ (d & 7);
        bf16x8 vf = __builtin_bit_cast(bf16x8, *(const u16x8*)&Vs[cur][d * 64 + ch * 8]);
        oacc[nt] = __builtin_amdgcn_mfma_f32_16x16x32_bf16(pf[k2], vf, oacc[nt], 0, 0, 0);
      }
    }
  };

  const int nt_tiles = qtB + 1;
  stage(0, 0);
  __syncthreads();
  for (int t = 0; t < nt_tiles; ++t) {
    int cur = t & 1;
    if (t + 1 < nt_tiles) stage(cur ^ 1, t + 1);
    int kv0 = t * 64;
    if (kv0 <= q0A + 15) do_ctx(qfA, oaccA, mA, lA, q0A, kv0, cur);
    if (kv0 <= q0B + 15) do_ctx(qfB, oaccB, mB, lB, q0B, kv0, cur);
    __syncthreads();
  }
  // epilogue: both contexts
  #pragma unroll
  for (int r = 0; r < 4; ++r) {
    float invA = 1.0f / lA[r], invB = 1.0f / lB[r];
    #pragma unroll
    for (int nt = 0; nt < 8; ++nt) {
      int col = h * HD + nt * 16 + (lane & 15);
      int rowA = b * SEQ + q0A + (lane >> 4) * 4 + r;
      int rowB = b * SEQ + q0B + (lane >> 4) * 4 + r;
      out[(size_t)rowA * HIDDEN + col] = f2bf(oaccA[nt][r] * invA);
      out[(size_t)rowB * HIDDEN + col] = f2bf(oaccB[nt][r] * invB);
    }
  }
}

extern "C" void kernel_launch(void* const* d_in, const int* in_sizes, int n_in,
                              void* d_out, int out_size, void* d_ws, size_t ws_size,
                              hipStream_t stream) {
  (void)in_sizes; (void)n_in; (void)out_size; (void)ws_size;
  const float* x  = (const float*)d_in[0];
  const float* wq = (const float*)d_in[1];
  const float* wk = (const float*)d_in[2];
  const float* wv = (const float*)d_in[3];
  const float* wo = (const float*)d_in[4];
  float* out = (float*)d_out;
  char* ws = (char*)d_ws;

  u16* xbf   = (u16*)(ws);                                         // 4096x2048 bf16 (16.8MB)
  u16* wqkvt = (u16*)(ws + (size_t)16777216);                      // 3072x2048 bf16 (12.6MB)
  u16* wot   = (u16*)(ws + (size_t)16777216 + 12582912);           // 2048x2048 bf16 (8.4MB)
  u16* qkv   = (u16*)(ws + (size_t)16777216 + 12582912 + 8388608); // 4096x3072 bf16 (25.2MB)
  u16* vtb   = (u16*)(ws + (size_t)16777216 + 12582912 + 8388608 + 25165824); // 8x128x2048 (4MB)
  u16* aout  = xbf;  // alias: X no longer needed after QKV GEMM

  cast_f32_bf16<<<4096, 256, 0, stream>>>(x, xbf, MROWS * HIDDEN / 8);
  transpose_cast<<<dim3(64, 64), dim3(32, 8), 0, stream>>>(wq, wqkvt, HIDDEN, 2048);
  transpose_cast<<<dim3(16, 64), dim3(32, 8), 0, stream>>>(wk, wqkvt + (size_t)2048 * 2048, HIDDEN, 512);
  transpose_cast<<<dim3(16, 64), dim3(32, 8), 0, stream>>>(wv, wqkvt + (size_t)2560 * 2048, HIDDEN, 512);
  transpose_cast<<<dim3(64, 64), dim3(32, 8), 0, stream>>>(wo, wot, HIDDEN, HIDDEN);

  gemm256<1><<<dim3(NQKV / 256, MROWS / 256), 512, 0, stream>>>(xbf, wqkvt, qkv, MROWS, NQKV, HIDDEN);
  rope_kernel<<<(MROWS * 20 * 64) / 256, 256, 0, stream>>>(qkv);
  vtrans_kernel<<<dim3(SEQ / 32, HD / 32, BATCH * NKV), dim3(32, 8), 0, stream>>>(qkv, vtb);
  attn_kernel<<<dim3(16, NH, BATCH), 256, 0, stream>>>(qkv, vtb, aout);
  gemm256<0><<<dim3(HIDDEN / 256, MROWS / 256), 512, 0, stream>>>(aout, wot, out, MROWS, HIDDEN, HIDDEN);
}

// Round 8
// 384.856 us; speedup vs baseline: 1.0058x; 1.0058x over previous
//
#include <hip/hip_runtime.h>

#define HIDDEN 2048
#define NH 16
#define NKV 4
#define HD 128
#define BATCH 2
#define SEQ 2048
#define MROWS (BATCH*SEQ)          // 4096
#define NQKV (NH*HD + 2*NKV*HD)    // 3072
#define KOFF (NH*HD)               // 2048
#define VOFF (NH*HD + NKV*HD)      // 2560

typedef unsigned short u16;
typedef unsigned int u32;
typedef __bf16 bf16_t;
typedef bf16_t bf16x8 __attribute__((ext_vector_type(8)));
typedef float f32x4 __attribute__((ext_vector_type(4)));
typedef u16 u16x8 __attribute__((ext_vector_type(8)));

__device__ __forceinline__ u16 f2bf(float f) {
  return __builtin_bit_cast(u16, (__bf16)f);   // compiler RNE
}
__device__ __forceinline__ float bf2f(u16 h) {
  u32 u = ((u32)h) << 16;
  return __builtin_bit_cast(float, u);
}

// ---------------- cast f32 -> bf16, 8 elems/thread ----------------
__global__ void cast_f32_bf16(const float* __restrict__ in, u16* __restrict__ out, int n8) {
  int i = blockIdx.x * blockDim.x + threadIdx.x;
  if (i >= n8) return;
  const float4* p = (const float4*)in + (size_t)i * 2;
  float4 a = p[0], b = p[1];
  u16x8 o;
  o[0]=f2bf(a.x); o[1]=f2bf(a.y); o[2]=f2bf(a.z); o[3]=f2bf(a.w);
  o[4]=f2bf(b.x); o[5]=f2bf(b.y); o[6]=f2bf(b.z); o[7]=f2bf(b.w);
  *((u16x8*)out + i) = o;
}

// ---------------- transpose + cast: src K x N f32 -> dst N x K bf16 ----------------
__global__ void transpose_cast(const float* __restrict__ src, u16* __restrict__ dst, int K, int N) {
  __shared__ float tile[32][33];
  int k0 = blockIdx.y * 32, n0 = blockIdx.x * 32;
  int tx = threadIdx.x, ty = threadIdx.y;
  #pragma unroll
  for (int j = 0; j < 32; j += 8)
    tile[ty + j][tx] = src[(size_t)(k0 + ty + j) * N + n0 + tx];
  __syncthreads();
  #pragma unroll
  for (int j = 0; j < 32; j += 8)
    dst[(size_t)(n0 + ty + j) * K + k0 + tx] = f2bf(tile[tx][ty + j]);
}

// ---------------- GEMM 256x128 tile, BK=64, 8 waves (4Mx2N), counted-vmcnt dbuf ----
// C[M,N] = A[M,K] * Bt[N,K]^T, bf16 in, f32 acc.
// LDS rows = 64 u16 (128B), 8 chunks of 16B, chunk slot ^= row&7 (both-sides swizzle:
// linear gload_lds dest + inverse-swizzled global src + swizzled ds_read).
// Counted vmcnt: stage(t+1) issued at top of iter t; s_waitcnt vmcnt(6) leaves exactly
// stage(t+1)'s 6 loads in flight -> no vmcnt(0) drain in the main loop (T4).
// Race-freedom: end-of-iter s_barrier ensures all waves' frag reads of buf^1 are done
// (MFMA consumption forced lgkmcnt waits) before iter t+1's stage overwrites it;
// per-wave vmcnt(6) + top s_barrier ensures every wave's stage landed before reads.
template<int OUT_BF16>
__global__ __launch_bounds__(512) void gemm8p(const u16* __restrict__ A, const u16* __restrict__ Bt,
                                              void* __restrict__ Cout, int M, int N, int K) {
  __shared__ u16 As[2][256 * 64];
  __shared__ u16 Bs[2][128 * 64];
  const int tid = threadIdx.x;
  const int lane = tid & 63, wave = tid >> 6;
  const int mb = blockIdx.y * 256, nb = blockIdx.x * 128;
  const int wm = (wave >> 1) * 64;       // 4 M-waves of 64 rows
  const int wn = (wave & 1) * 64;        // 2 N-waves of 64 cols
  const int NT = K >> 6;

  // stage mapping: chunk c = j*512 + tid -> row = j*64 + (tid>>3), slot = tid&7
  const int rsub = tid >> 3;
  const int scol = (tid & 7) ^ (rsub & 7);     // inverse swizzle (involution)
  const int wbase = tid & ~63;                 // wave-uniform chunk base

  auto stage = [&](int buf, int kt) {
    #pragma unroll
    for (int j = 0; j < 4; ++j) {              // A: 256 rows
      int r = j * 64 + rsub;
      const u16* ga = A + (size_t)(mb + r) * K + kt * 64 + scol * 8;
      __builtin_amdgcn_global_load_lds((const __attribute__((address_space(1))) u32*)ga,
          (__attribute__((address_space(3))) u32*)&As[buf][(j * 512 + wbase) * 8], 16, 0, 0);
    }
    #pragma unroll
    for (int j = 0; j < 2; ++j) {              // B: 128 rows
      int r = j * 64 + rsub;
      const u16* gb = Bt + (size_t)(nb + r) * K + kt * 64 + scol * 8;
      __builtin_amdgcn_global_load_lds((const __attribute__((address_space(1))) u32*)gb,
          (__attribute__((address_space(3))) u32*)&Bs[buf][(j * 512 + wbase) * 8], 16, 0, 0);
    }
  };

  f32x4 acc[4][4];
  #pragma unroll
  for (int i = 0; i < 4; ++i)
    #pragma unroll
    for (int j = 0; j < 4; ++j) acc[i][j] = (f32x4)0.0f;

  const int frow = lane & 15;
  const int fhi = lane >> 4;

  stage(0, 0);
  __syncthreads();                             // prologue: full drain once

  for (int t = 0; t < NT; ++t) {
    int cur = t & 1;
    if (t + 1 < NT) {
      stage(cur ^ 1, t + 1);                   // 6 loads issued
      asm volatile("s_waitcnt vmcnt(6)" ::: "memory");  // stage(t) landed; t+1 in flight
    } else {
      asm volatile("s_waitcnt vmcnt(0)" ::: "memory");
    }
    __builtin_amdgcn_s_barrier();              // all waves: buf[cur] ready (no drain)

    // B frags held across both phases (8 ds_read_b128, 32 VGPR)
    bf16x8 bfr[4][2];
    #pragma unroll
    for (int ni = 0; ni < 4; ++ni)
      #pragma unroll
      for (int kk = 0; kk < 2; ++kk) {
        int row = wn + ni * 16 + frow;
        int ch = (kk * 4 + fhi) ^ (row & 7);
        bfr[ni][kk] = __builtin_bit_cast(bf16x8, *(const u16x8*)&Bs[cur][row * 64 + ch * 8]);
      }
    // 2 phases over M halves: 4 ds_read + 16 MFMA each
    #pragma unroll
    for (int ph = 0; ph < 2; ++ph) {
      bf16x8 af[2][2];
      #pragma unroll
      for (int mi = 0; mi < 2; ++mi)
        #pragma unroll
        for (int kk = 0; kk < 2; ++kk) {
          int row = wm + (ph * 2 + mi) * 16 + frow;
          int ch = (kk * 4 + fhi) ^ (row & 7);
          af[mi][kk] = __builtin_bit_cast(bf16x8, *(const u16x8*)&As[cur][row * 64 + ch * 8]);
        }
      __builtin_amdgcn_s_setprio(1);
      #pragma unroll
      for (int mi = 0; mi < 2; ++mi)
        #pragma unroll
        for (int ni = 0; ni < 4; ++ni)
          #pragma unroll
          for (int kk = 0; kk < 2; ++kk)
            acc[ph * 2 + mi][ni] = __builtin_amdgcn_mfma_f32_16x16x32_bf16(
                af[mi][kk], bfr[ni][kk], acc[ph * 2 + mi][ni], 0, 0, 0);
      __builtin_amdgcn_s_setprio(0);
    }
    __builtin_amdgcn_s_barrier();              // all reads of buf[cur] done
  }

  // epilogue: C/D layout col = lane&15, row = (lane>>4)*4 + reg
  int rbase = mb + wm + fhi * 4;
  int cbase = nb + wn + frow;
  #pragma unroll
  for (int mi = 0; mi < 4; ++mi) {
    #pragma unroll
    for (int r = 0; r < 4; ++r) {
      int row = rbase + mi * 16 + r;
      #pragma unroll
      for (int ni = 0; ni < 4; ++ni) {
        int col = cbase + ni * 16;
        float v = acc[mi][ni][r];
        if (OUT_BF16) ((u16*)Cout)[(size_t)row * N + col] = f2bf(v);
        else          ((float*)Cout)[(size_t)row * N + col] = v;
      }
    }
  }
}

// ---------------- RoPE in-place on QKV (bf16), Q heads 0..15, K heads 0..3 ----------------
__global__ void rope_kernel(u16* __restrict__ qkv) {
  int idx = blockIdx.x * blockDim.x + threadIdx.x;   // < MROWS*20*64
  int d = idx & 63;
  int t = idx >> 6;
  int hd = t % 20;
  int row = t / 20;
  int s = row & (SEQ - 1);
  int cb = (hd < NH) ? hd * HD : KOFF + (hd - NH) * HD;
  float inv = __expf((float)d * -0.14391156f);   // 10000^(-d/64)
  float freq = (float)s * inv;
  float sn = sinf(freq), cs = cosf(freq);
  size_t base = (size_t)row * NQKV + cb + d;
  float x0 = bf2f(qkv[base]), x1 = bf2f(qkv[base + 64]);
  qkv[base]      = f2bf(x0 * cs - x1 * sn);
  qkv[base + 64] = f2bf(x1 * cs + x0 * sn);
}

// ---------------- transpose V section of QKV into VT (b,kvh,d,s) ----------------
__global__ void vtrans_kernel(const u16* __restrict__ qkv, u16* __restrict__ vt) {
  __shared__ u16 tile[32][33];
  int bh = blockIdx.z;            // b*NKV + kvh
  int d0 = blockIdx.y * 32;
  int s0 = blockIdx.x * 32;
  int b = bh >> 2, kvh = bh & 3;
  int tx = threadIdx.x, ty = threadIdx.y;
  const u16* src = qkv + (size_t)(b * SEQ) * NQKV + VOFF + kvh * HD;
  #pragma unroll
  for (int j = 0; j < 32; j += 8)
    tile[ty + j][tx] = src[(size_t)(s0 + ty + j) * NQKV + d0 + tx];
  __syncthreads();
  u16* dst = vt + (size_t)bh * HD * SEQ;
  #pragma unroll
  for (int j = 0; j < 32; j += 8)
    dst[(size_t)(d0 + ty + j) * SEQ + s0 + tx] = tile[tx][ty + j];
}

// ---------------- flash attention, causal, GQA, paired q-tiles (unchanged r6) ----------------
__global__ __launch_bounds__(256, 2) void attn_kernel(const u16* __restrict__ qkv,
                                                      const u16* __restrict__ vt,
                                                      u16* __restrict__ out) {
  __shared__ u16 Ks[2][64 * 128];   // [kv][d], 256B rows, slot ^= kv&7
  __shared__ u16 Vs[2][128 * 64];   // [d][kv], 128B rows, slot ^= d&7
  __shared__ u16 Ps[4][16 * 64];    // per-wave [q][kv], 128B rows, slot ^= q&7
  const int tid = threadIdx.x, lane = tid & 63, wave = tid >> 6;
  const int qtA = blockIdx.x, qtB = 31 - qtA;
  const int h = blockIdx.y, b = blockIdx.z;
  const int kvh = h >> 2;
  const int q0A = qtA * 64 + wave * 16;
  const int q0B = qtB * 64 + wave * 16;
  const float scale2 = 0.12751743f;  // 1/sqrt(128) * log2(e)

  const u16* kbase = qkv + (size_t)(b * SEQ) * NQKV + KOFF + kvh * HD;
  const u16* vbase = vt + (size_t)(b * NKV + kvh) * HD * SEQ;

  bf16x8 qfA[4], qfB[4];
  {
    const u16* qa = qkv + (size_t)(b * SEQ + q0A + (lane & 15)) * NQKV + h * HD + (lane >> 4) * 8;
    const u16* qb = qkv + (size_t)(b * SEQ + q0B + (lane & 15)) * NQKV + h * HD + (lane >> 4) * 8;
    #pragma unroll
    for (int kc = 0; kc < 4; ++kc) {
      qfA[kc] = __builtin_bit_cast(bf16x8, *(const u16x8*)(qa + kc * 32));
      qfB[kc] = __builtin_bit_cast(bf16x8, *(const u16x8*)(qb + kc * 32));
    }
  }
  f32x4 oaccA[8], oaccB[8];
  float mA[4], lA[4], mB[4], lB[4];
  #pragma unroll
  for (int i = 0; i < 8; ++i) { oaccA[i] = (f32x4)0.0f; oaccB[i] = (f32x4)0.0f; }
  #pragma unroll
  for (int r = 0; r < 4; ++r) { mA[r] = -INFINITY; lA[r] = 0.0f; mB[r] = -INFINITY; lB[r] = 0.0f; }

  const int krow = tid >> 4;
  const int kslot = (tid & 15) ^ (krow & 7);
  const int vrow = tid >> 3;
  const int vslot = (tid & 7) ^ (vrow & 7);
  const int wbase = (tid & ~63);

  auto stage = [&](int buf, int t) {
    int kv0 = t * 64;
    #pragma unroll
    for (int j = 0; j < 4; ++j) {
      const u16* src = kbase + (size_t)(kv0 + j * 16 + krow) * NQKV + kslot * 8;
      __builtin_amdgcn_global_load_lds((const __attribute__((address_space(1))) u32*)src,
          (__attribute__((address_space(3))) u32*)&Ks[buf][(j * 256 + wbase) * 8], 16, 0, 0);
    }
    #pragma unroll
    for (int j = 0; j < 4; ++j) {
      const u16* src = vbase + (size_t)(j * 32 + vrow) * SEQ + kv0 + vslot * 8;
      __builtin_amdgcn_global_load_lds((const __attribute__((address_space(1))) u32*)src,
          (__attribute__((address_space(3))) u32*)&Vs[buf][(j * 256 + wbase) * 8], 16, 0, 0);
    }
  };

  auto do_ctx = [&](const bf16x8 (&qf)[4], f32x4 (&oacc)[8], float (&mr)[4], float (&lr)[4],
                    int q0c, int kv0, int cur) {
    f32x4 sacc[4];
    #pragma unroll
    for (int n2 = 0; n2 < 4; ++n2) sacc[n2] = (f32x4)0.0f;
    #pragma unroll
    for (int n2 = 0; n2 < 4; ++n2) {
      int kvr = n2 * 16 + (lane & 15);
      #pragma unroll
      for (int kc = 0; kc < 4; ++kc) {
        int ch = (kc * 4 + (lane >> 4)) ^ (kvr & 7);
        bf16x8 kf = __builtin_bit_cast(bf16x8, *(const u16x8*)&Ks[cur][kvr * 128 + ch * 8]);
        sacc[n2] = __builtin_amdgcn_mfma_f32_16x16x32_bf16(qf[kc], kf, sacc[n2], 0, 0, 0);
      }
    }
    const bool full = (kv0 + 63 <= q0c);
    u16* pwb = &Ps[wave][0];
    #pragma unroll
    for (int r = 0; r < 4; ++r) {
      int qr = (lane >> 4) * 4 + r;
      float p0, p1, p2, p3;
      if (full) {
        p0 = sacc[0][r] * scale2; p1 = sacc[1][r] * scale2;
        p2 = sacc[2][r] * scale2; p3 = sacc[3][r] * scale2;
      } else {
        int q = q0c + qr;
        int kvc = kv0 + (lane & 15);
        p0 = (kvc       <= q) ? sacc[0][r] * scale2 : -INFINITY;
        p1 = (kvc + 16  <= q) ? sacc[1][r] * scale2 : -INFINITY;
        p2 = (kvc + 32  <= q) ? sacc[2][r] * scale2 : -INFINITY;
        p3 = (kvc + 48  <= q) ? sacc[3][r] * scale2 : -INFINITY;
      }
      float v = fmaxf(fmaxf(p0, p1), fmaxf(p2, p3));
      v = fmaxf(v, __shfl_xor(v, 1));
      v = fmaxf(v, __shfl_xor(v, 2));
      v = fmaxf(v, __shfl_xor(v, 4));
      v = fmaxf(v, __shfl_xor(v, 8));
      float m = mr[r];
      if (v > m + 8.0f) {
        float corr = exp2f(m - v);
        lr[r] *= corr;
        #pragma unroll
        for (int nt = 0; nt < 8; ++nt) oacc[nt][r] *= corr;
        m = v; mr[r] = v;
      }
      float e0 = exp2f(p0 - m), e1 = exp2f(p1 - m);
      float e2 = exp2f(p2 - m), e3 = exp2f(p3 - m);
      float ps = (e0 + e1) + (e2 + e3);
      ps += __shfl_xor(ps, 1);
      ps += __shfl_xor(ps, 2);
      ps += __shfl_xor(ps, 4);
      ps += __shfl_xor(ps, 8);
      lr[r] += ps;
      char* base = (char*)pwb + qr * 128 + (lane & 7) * 2;
      int half = (lane & 15) >> 3;
      *(u16*)(base + (((0 + half) ^ (qr & 7)) << 4)) = f2bf(e0);
      *(u16*)(base + (((2 + half) ^ (qr & 7)) << 4)) = f2bf(e1);
      *(u16*)(base + (((4 + half) ^ (qr & 7)) << 4)) = f2bf(e2);
      *(u16*)(base + (((6 + half) ^ (qr & 7)) << 4)) = f2bf(e3);
    }
    asm volatile("s_waitcnt lgkmcnt(0)" ::: "memory");
    bf16x8 pf[2];
    #pragma unroll
    for (int k2 = 0; k2 < 2; ++k2) {
      int q = lane & 15;
      int ch = (k2 * 4 + (lane >> 4)) ^ (q & 7);
      pf[k2] = __builtin_bit_cast(bf16x8, *(const u16x8*)((const char*)pwb + q * 128 + ch * 16));
    }
    #pragma unroll
    for (int nt = 0; nt < 8; ++nt) {
      int d = nt * 16 + (lane & 15);
      #pragma unroll
      for (int k2 = 0; k2 < 2; ++k2) {
        int ch = (k2 * 4 + (lane >> 4)) ^ (d & 7);
        bf16x8 vf = __builtin_bit_cast(bf16x8, *(const u16x8*)&Vs[cur][d * 64 + ch * 8]);
        oacc[nt] = __builtin_amdgcn_mfma_f32_16x16x32_bf16(pf[k2], vf, oacc[nt], 0, 0, 0);
      }
    }
  };

  const int nt_tiles = qtB + 1;
  stage(0, 0);
  __syncthreads();
  for (int t = 0; t < nt_tiles; ++t) {
    int cur = t & 1;
    if (t + 1 < nt_tiles) stage(cur ^ 1, t + 1);
    int kv0 = t * 64;
    if (kv0 <= q0A + 15) do_ctx(qfA, oaccA, mA, lA, q0A, kv0, cur);
    if (kv0 <= q0B + 15) do_ctx(qfB, oaccB, mB, lB, q0B, kv0, cur);
    __syncthreads();
  }
  #pragma unroll
  for (int r = 0; r < 4; ++r) {
    float invA = 1.0f / lA[r], invB = 1.0f / lB[r];
    #pragma unroll
    for (int nt = 0; nt < 8; ++nt) {
      int col = h * HD + nt * 16 + (lane & 15);
      int rowA = b * SEQ + q0A + (lane >> 4) * 4 + r;
      int rowB = b * SEQ + q0B + (lane >> 4) * 4 + r;
      out[(size_t)rowA * HIDDEN + col] = f2bf(oaccA[nt][r] * invA);
      out[(size_t)rowB * HIDDEN + col] = f2bf(oaccB[nt][r] * invB);
    }
  }
}

extern "C" void kernel_launch(void* const* d_in, const int* in_sizes, int n_in,
                              void* d_out, int out_size, void* d_ws, size_t ws_size,
                              hipStream_t stream) {
  (void)in_sizes; (void)n_in; (void)out_size; (void)ws_size;
  const float* x  = (const float*)d_in[0];
  const float* wq = (const float*)d_in[1];
  const float* wk = (const float*)d_in[2];
  const float* wv = (const float*)d_in[3];
  const float* wo = (const float*)d_in[4];
  float* out = (float*)d_out;
  char* ws = (char*)d_ws;

  u16* xbf   = (u16*)(ws);                                         // 4096x2048 bf16 (16.8MB)
  u16* wqkvt = (u16*)(ws + (size_t)16777216);                      // 3072x2048 bf16 (12.6MB)
  u16* wot   = (u16*)(ws + (size_t)16777216 + 12582912);           // 2048x2048 bf16 (8.4MB)
  u16* qkv   = (u16*)(ws + (size_t)16777216 + 12582912 + 8388608); // 4096x3072 bf16 (25.2MB)
  u16* vtb   = (u16*)(ws + (size_t)16777216 + 12582912 + 8388608 + 25165824); // 8x128x2048 (4MB)
  u16* aout  = xbf;  // alias: X no longer needed after QKV GEMM

  cast_f32_bf16<<<4096, 256, 0, stream>>>(x, xbf, MROWS * HIDDEN / 8);
  transpose_cast<<<dim3(64, 64), dim3(32, 8), 0, stream>>>(wq, wqkvt, HIDDEN, 2048);
  transpose_cast<<<dim3(16, 64), dim3(32, 8), 0, stream>>>(wk, wqkvt + (size_t)2048 * 2048, HIDDEN, 512);
  transpose_cast<<<dim3(16, 64), dim3(32, 8), 0, stream>>>(wv, wqkvt + (size_t)2560 * 2048, HIDDEN, 512);
  transpose_cast<<<dim3(64, 64), dim3(32, 8), 0, stream>>>(wo, wot, HIDDEN, HIDDEN);

  gemm8p<1><<<dim3(NQKV / 128, MROWS / 256), 512, 0, stream>>>(xbf, wqkvt, qkv, MROWS, NQKV, HIDDEN);
  rope_kernel<<<(MROWS * 20 * 64) / 256, 256, 0, stream>>>(qkv);
  vtrans_kernel<<<dim3(SEQ / 32, HD / 32, BATCH * NKV), dim3(32, 8), 0, stream>>>(qkv, vtb);
  attn_kernel<<<dim3(16, NH, BATCH), 256, 0, stream>>>(qkv, vtb, aout);
  gemm8p<0><<<dim3(HIDDEN / 128, MROWS / 256), 512, 0, stream>>>(aout, wot, out, MROWS, HIDDEN, HIDDEN);
}